// Round 12
// baseline (1128.386 us; speedup 1.0000x reference)
//
#include <hip/hip_runtime.h>
#include <hip/hip_bf16.h>
#include <math.h>

#define SL     1024
#define DMODEL 768
#define NLAYER 4
#define NSTATE 64
#define HEADDIM 64
#define DINNER 1536
#define NHEADS 24
#define CONVDIM 1664
#define DINPROJ 3224
#define VOCABN 50257

typedef __attribute__((ext_vector_type(8))) short short8;
typedef __attribute__((ext_vector_type(4))) short short4v;
typedef __attribute__((ext_vector_type(4))) float f32x4;

__device__ __forceinline__ short f2bf(float f) {
    unsigned int u = __builtin_bit_cast(unsigned int, f);
    u += 0x7fffu + ((u >> 16) & 1u);
    return (short)(u >> 16);
}

#define AS1 __attribute__((address_space(1)))
#define AS3 __attribute__((address_space(3)))
__device__ __forceinline__ void gl2lds16(const void* g, void* l) {
    __builtin_amdgcn_global_load_lds((const AS1 unsigned int*)g,
                                     (AS3 unsigned int*)(unsigned int)(uintptr_t)l,
                                     16, 0, 0);
}

template <int CTRL>
__device__ __forceinline__ float dppadd(float x) {
    int v = __builtin_amdgcn_update_dpp(0, __builtin_bit_cast(int, x), CTRL, 0xf, 0xf, true);
    return x + __builtin_bit_cast(float, v);
}

// ---------------- fp32 -> bf16 bulk convert ----------------
__global__ void cvt_k(const float* __restrict__ s, short* __restrict__ d, int n) {
    int i = (blockIdx.x * 256 + threadIdx.x) * 4;
    if (i >= n) return;
    float4 v = *(const float4*)(s + i);
    short4v o;
    o.x = f2bf(v.x); o.y = f2bf(v.y); o.z = f2bf(v.z); o.w = f2bf(v.w);
    *(short4v*)(d + i) = o;
}

// ---------------- zero fill (float4) ----------------
__global__ void zero_k(float* __restrict__ p, int n4) {
    int i = blockIdx.x * 256 + threadIdx.x;
    if (i < n4) *(float4*)(p + i * 4) = make_float4(0.f, 0.f, 0.f, 0.f);
}

// ---------------- embedding gather ----------------
__global__ void embed_k(const int* __restrict__ idx, const float* __restrict__ emb,
                        float* __restrict__ x) {
    int d = blockIdx.x * 256 + threadIdx.x;
    int t = blockIdx.y;
    x[t * DMODEL + d] = emb[(size_t)idx[t] * DMODEL + d];
}

// ---------------- layernorm (768), out bf16 ----------------
__global__ void ln_k(const float* __restrict__ x, const float* __restrict__ w,
                     const float* __restrict__ b, short* __restrict__ out) {
    int row = blockIdx.x, t = threadIdx.x;
    const float* xr = x + row * DMODEL;
    float v0 = xr[t], v1 = xr[t + 256], v2 = xr[t + 512];
    float s = v0 + v1 + v2;
    float q = v0 * v0 + v1 * v1 + v2 * v2;
    __shared__ float sa[4], sb[4];
    for (int off = 32; off; off >>= 1) { s += __shfl_down(s, off); q += __shfl_down(q, off); }
    if (!(t & 63)) { sa[t >> 6] = s; sb[t >> 6] = q; }
    __syncthreads();
    s = sa[0] + sa[1] + sa[2] + sa[3];
    q = sb[0] + sb[1] + sb[2] + sb[3];
    float mean = s * (1.f / DMODEL);
    float var  = q * (1.f / DMODEL) - mean * mean;
    float rs = rsqrtf(var + 1e-5f);
    out[row * DMODEL + t      ] = f2bf((v0 - mean) * rs * w[t      ] + b[t      ]);
    out[row * DMODEL + t + 256] = f2bf((v1 - mean) * rs * w[t + 256] + b[t + 256]);
    out[row * DMODEL + t + 512] = f2bf((v2 - mean) * rs * w[t + 512] + b[t + 512]);
}

// ---------------- GEMM v9 (logits): C[m,n] = sum_k A_bf16[m,k] * B_bf16[n,k] ------
// (round-8 best: 235 us, frozen) 256x256 tile, BK=64, 512 threads (8 waves, 2m x 4n).
// 4-phase schedule with counted vmcnt(4); vmcnt(0) only in final tile tail.
// LDS [buf][kk (2)][q (4)][row (256)][8 shorts]. Fused NLL epilogue (two-pass).
__global__ __launch_bounds__(512) void gemm_bb_k(const short* __restrict__ A,
                                                 const short* __restrict__ B,
                                                 float* __restrict__ C,
                                                 float2* __restrict__ P,
                                                 int N, int K, int addflag) {
    __shared__ __align__(16) short As[2][16384];  // [buf][kk*8192 + q*2048 + row*8]
    __shared__ __align__(16) short Bs[2][16384];
    const int t = threadIdx.x;
    const int lane = t & 63, wv = t >> 6;

    const int nwg = gridDim.x;
    int bid = blockIdx.x;
    int qq = nwg >> 3, rr = nwg & 7;
    int xcd = bid & 7, ii = bid >> 3;
    int v = (xcd < rr ? xcd * (qq + 1) : rr * (qq + 1) + (xcd - rr) * qq) + ii;
    const int m0 = (v & 3) * 256;          // 4 m-blocks (M = 1024)
    const int n0 = (v >> 2) * 256;

    const int wm = (wv >> 2) * 128, wn = (wv & 3) * 64;
    const int q4 = lane >> 4, l16 = lane & 15;

    f32x4 zero4 = {0.f, 0.f, 0.f, 0.f};
    f32x4 acc[8][4];
#pragma unroll
    for (int i = 0; i < 8; i++)
#pragma unroll
        for (int j = 0; j < 4; j++) acc[i][j] = zero4;

    auto stageA = [&](int buf, int kh, int k0) {
#pragma unroll
        for (int i = 0; i < 2; i++) {
            int g = i * 512 + t;            // 0..1023
            int q = g >> 8, r = g & 255;
            gl2lds16(A + (size_t)(m0 + r) * K + k0 + kh * 32 + q * 8,
                     &As[buf][kh * 8192 + g * 8]);
        }
    };
    auto stageB = [&](int buf, int kh, int k0) {
#pragma unroll
        for (int i = 0; i < 2; i++) {
            int g = i * 512 + t;
            int q = g >> 8, r = g & 255;
            int gr = n0 + r; if (gr > N - 1) gr = N - 1;
            gl2lds16(B + (size_t)gr * K + k0 + kh * 32 + q * 8,
                     &Bs[buf][kh * 8192 + g * 8]);
        }
    };

    const int NT = K >> 6;                 // BK = 64 (NT = 12)
    stageA(0, 0, 0); stageB(0, 0, 0); stageA(0, 1, 0); stageB(0, 1, 0);
    asm volatile("s_waitcnt vmcnt(4)" ::: "memory");
    __builtin_amdgcn_s_barrier();

    for (int tt = 0; tt < NT; tt++) {
        const int cur = tt & 1;
        const bool pf = (tt + 1 < NT);
        const int k1 = (tt + 1) << 6;
        const short* Ac = &As[cur][0];
        const short* Bc = &Bs[cur][0];

        short8 bfk[4];
        // ---- phase 0: kk=0, mt 0..3 ; stage AK0(t+1) ----
        {
            short8 af[4];
#pragma unroll
            for (int nt = 0; nt < 4; nt++)
                bfk[nt] = *(const short8*)(Bc + q4 * 2048 + (wn + nt * 16 + l16) * 8);
#pragma unroll
            for (int mt = 0; mt < 4; mt++)
                af[mt] = *(const short8*)(Ac + q4 * 2048 + (wm + mt * 16 + l16) * 8);
            if (pf) stageA(cur ^ 1, 0, k1);
            __builtin_amdgcn_s_barrier();
            __builtin_amdgcn_s_setprio(1);
#pragma unroll
            for (int mt = 0; mt < 4; mt++)
#pragma unroll
                for (int nt = 0; nt < 4; nt++)
                    acc[mt][nt] = __builtin_amdgcn_mfma_f32_16x16x32_bf16(af[mt], bfk[nt], acc[mt][nt], 0, 0, 0);
            __builtin_amdgcn_s_setprio(0);
            __builtin_amdgcn_s_barrier();
        }
        // ---- phase 1: kk=0, mt 4..7 ; stage BK0(t+1) ; wait K-half1 ----
        {
            short8 af[4];
#pragma unroll
            for (int mt = 0; mt < 4; mt++)
                af[mt] = *(const short8*)(Ac + q4 * 2048 + (wm + (mt + 4) * 16 + l16) * 8);
            if (pf) stageB(cur ^ 1, 0, k1);
            __builtin_amdgcn_s_barrier();
            __builtin_amdgcn_s_setprio(1);
#pragma unroll
            for (int mt = 0; mt < 4; mt++)
#pragma unroll
                for (int nt = 0; nt < 4; nt++)
                    acc[mt + 4][nt] = __builtin_amdgcn_mfma_f32_16x16x32_bf16(af[mt], bfk[nt], acc[mt + 4][nt], 0, 0, 0);
            __builtin_amdgcn_s_setprio(0);
            if (pf) asm volatile("s_waitcnt vmcnt(4)" ::: "memory");
            else    asm volatile("s_waitcnt vmcnt(0)" ::: "memory");
            __builtin_amdgcn_s_barrier();
        }
        // ---- phase 2: kk=1, mt 0..3 ; stage AK1(t+1) ----
        {
            short8 af[4];
#pragma unroll
            for (int nt = 0; nt < 4; nt++)
                bfk[nt] = *(const short8*)(Bc + 8192 + q4 * 2048 + (wn + nt * 16 + l16) * 8);
#pragma unroll
            for (int mt = 0; mt < 4; mt++)
                af[mt] = *(const short8*)(Ac + 8192 + q4 * 2048 + (wm + mt * 16 + l16) * 8);
            if (pf) stageA(cur ^ 1, 1, k1);
            __builtin_amdgcn_s_barrier();
            __builtin_amdgcn_s_setprio(1);
#pragma unroll
            for (int mt = 0; mt < 4; mt++)
#pragma unroll
                for (int nt = 0; nt < 4; nt++)
                    acc[mt][nt] = __builtin_amdgcn_mfma_f32_16x16x32_bf16(af[mt], bfk[nt], acc[mt][nt], 0, 0, 0);
            __builtin_amdgcn_s_setprio(0);
            __builtin_amdgcn_s_barrier();
        }
        // ---- phase 3: kk=1, mt 4..7 ; stage BK1(t+1) ; wait next K-half0 ----
        {
            short8 af[4];
#pragma unroll
            for (int mt = 0; mt < 4; mt++)
                af[mt] = *(const short8*)(Ac + 8192 + q4 * 2048 + (wm + (mt + 4) * 16 + l16) * 8);
            if (pf) stageB(cur ^ 1, 1, k1);
            __builtin_amdgcn_s_barrier();
            __builtin_amdgcn_s_setprio(1);
#pragma unroll
            for (int mt = 0; mt < 4; mt++)
#pragma unroll
                for (int nt = 0; nt < 4; nt++)
                    acc[mt + 4][nt] = __builtin_amdgcn_mfma_f32_16x16x32_bf16(af[mt], bfk[nt], acc[mt + 4][nt], 0, 0, 0);
            __builtin_amdgcn_s_setprio(0);
            if (pf) asm volatile("s_waitcnt vmcnt(4)" ::: "memory");
            else    asm volatile("s_waitcnt vmcnt(0)" ::: "memory");
            __builtin_amdgcn_s_barrier();
        }
    }

    // ---- C store ----
#pragma unroll
    for (int mt = 0; mt < 8; mt++) {
        int row = m0 + wm + mt * 16 + q4 * 4;
#pragma unroll
        for (int nt = 0; nt < 4; nt++) {
            int col = n0 + wn + nt * 16 + l16;
            if (col < N) {
#pragma unroll
                for (int r = 0; r < 4; r++) {
                    size_t o = (size_t)(row + r) * N + col;
                    float val = acc[mt][nt][r];
                    if (addflag) C[o] += val; else C[o] = val;
                }
            }
        }
    }

    // ---- fused per-row logsumexp partial (two-pass: max, then sum-exp) ----
    float2* lds_ms = (float2*)&As[0][0];   // [256 rows][stride 5], 10 KB (padded)
    const int nw = wv & 3;
#pragma unroll
    for (int mt = 0; mt < 8; mt++) {
#pragma unroll
        for (int r = 0; r < 4; r++) {
            float m = -3.0e38f;
#pragma unroll
            for (int nt = 0; nt < 4; nt++) {
                int col = n0 + wn + nt * 16 + l16;
                if (col < N) m = fmaxf(m, acc[mt][nt][r]);
            }
#pragma unroll
            for (int off = 1; off < 16; off <<= 1)
                m = fmaxf(m, __shfl_xor(m, off));
            float s = 0.f;
#pragma unroll
            for (int nt = 0; nt < 4; nt++) {
                int col = n0 + wn + nt * 16 + l16;
                if (col < N) s += __expf(acc[mt][nt][r] - m);
            }
#pragma unroll
            for (int off = 1; off < 16; off <<= 1)
                s += __shfl_xor(s, off);
            if (l16 == 0)
                lds_ms[(wm + mt * 16 + q4 * 4 + r) * 5 + nw] = make_float2(m, s);
        }
    }
    __syncthreads();
    if (t < 256) {
        float m = -3.0e38f, s = 0.f;
#pragma unroll
        for (int w = 0; w < 4; w++) {
            float2 p = lds_ms[t * 5 + w];
            float nm = fmaxf(m, p.x);
            s = s * __expf(m - nm) + p.y * __expf(p.x - nm);
            m = nm;
        }
        P[(size_t)(v >> 2) * 1024 + (m0 + t)] = make_float2(m, s);
    }
}

// ---------------- GEMM v2 (128-tile, 2-phase, optional split-K) ------------------
// BM=BN=128, BK=32, 256 threads, wave tile 64x64 (4x4 of 16x16x32 MFMA).
// Counted vmcnt(4). 1-D grid (div by 8) + bijective XCD swizzle.
// Split-K: grid = nMB*nNB*nSplit; each split covers K/nSplit; stores via atomicAdd
// (C must be pre-zeroed or hold the accumulation base).
__global__ __launch_bounds__(256) void gemm128_k(const short* __restrict__ A,
                                                 const short* __restrict__ B,
                                                 float* __restrict__ C,
                                                 int N, int K, int addflag,
                                                 int nMB, int nSplit) {
    __shared__ __align__(16) short As[2][4096];  // per buf: 4 q * 128 r * 8 = 8 KB
    __shared__ __align__(16) short Bs[2][4096];
    const int t = threadIdx.x;
    const int lane = t & 63, wv = t >> 6;

    const int nwg = gridDim.x;
    int bid = blockIdx.x;
    int qq = nwg >> 3, rr = nwg & 7;
    int xcd = bid & 7, ii = bid >> 3;
    int v = (xcd < rr ? xcd * (qq + 1) : rr * (qq + 1) + (xcd - rr) * qq) + ii;
    const int tiles = nwg / nSplit;
    const int kr = v / tiles, rem = v % tiles;
    const int m0 = (rem % nMB) * 128, n0 = (rem / nMB) * 128;
    const int KS = K / nSplit;
    const int kb = kr * KS;

    const int wm = (wv >> 1) * 64, wn = (wv & 1) * 64;
    const int q4 = lane >> 4, l16 = lane & 15;

    f32x4 zero4 = {0.f, 0.f, 0.f, 0.f};
    f32x4 acc[4][4];
#pragma unroll
    for (int i = 0; i < 4; i++)
#pragma unroll
        for (int j = 0; j < 4; j++) acc[i][j] = zero4;

    auto stage = [&](int buf, int k0) {
#pragma unroll
        for (int i = 0; i < 2; i++) {
            int g = i * 256 + t;            // granule 0..511
            int q = g >> 7, r = g & 127;
            gl2lds16(A + (size_t)(m0 + r) * K + kb + k0 + q * 8, &As[buf][g * 8]);
        }
#pragma unroll
        for (int i = 0; i < 2; i++) {
            int g = i * 256 + t;
            int q = g >> 7, r = g & 127;
            int gr = n0 + r; if (gr > N - 1) gr = N - 1;
            gl2lds16(B + (size_t)gr * K + kb + k0 + q * 8, &Bs[buf][g * 8]);
        }
    };

    const int NT = KS >> 5;
    stage(0, 0);
    for (int tt = 0; tt < NT; tt++) {
        const int cur = tt & 1;
        if (tt + 1 < NT) {
            stage(cur ^ 1, (tt + 1) << 5);
            asm volatile("s_waitcnt vmcnt(4)" ::: "memory");
        } else {
            asm volatile("s_waitcnt vmcnt(0)" ::: "memory");
        }
        __builtin_amdgcn_s_barrier();

        short8 af[4], bf[4];
#pragma unroll
        for (int mt = 0; mt < 4; mt++)
            af[mt] = *(const short8*)(&As[cur][q4 * 1024 + (wm + mt * 16 + l16) * 8]);
#pragma unroll
        for (int nt = 0; nt < 4; nt++)
            bf[nt] = *(const short8*)(&Bs[cur][q4 * 1024 + (wn + nt * 16 + l16) * 8]);
        asm volatile("s_waitcnt lgkmcnt(0)" ::: "memory");
        __builtin_amdgcn_s_barrier();

#pragma unroll
        for (int mt = 0; mt < 4; mt++)
#pragma unroll
            for (int nt = 0; nt < 4; nt++)
                acc[mt][nt] = __builtin_amdgcn_mfma_f32_16x16x32_bf16(af[mt], bf[nt], acc[mt][nt], 0, 0, 0);
    }

#pragma unroll
    for (int mt = 0; mt < 4; mt++) {
        int row = m0 + wm + mt * 16 + (lane >> 4) * 4;
#pragma unroll
        for (int nt = 0; nt < 4; nt++) {
            int col = n0 + wn + nt * 16 + l16;
            if (col < N) {
#pragma unroll
                for (int r = 0; r < 4; r++) {
                    size_t o = (size_t)(row + r) * N + col;
                    float val = acc[mt][nt][r];
                    if (nSplit > 1) atomicAdd(&C[o], val);
                    else if (addflag) C[o] += val;
                    else C[o] = val;
                }
            }
        }
    }
}

// ---------------- GEMM v3 (64-tile, 2-phase, optional split-K) -------------------
// BM=BN=64, BK=64, 256 threads, wave tile 32x32 (2x2 of 16x16x32 MFMA).
__global__ __launch_bounds__(256) void gemm64_k(const short* __restrict__ A,
                                                const short* __restrict__ B,
                                                float* __restrict__ C,
                                                int N, int K, int addflag,
                                                int nMB, int nSplit) {
    __shared__ __align__(16) short As[2][4096];  // per buf: 8 q * 64 r * 8
    __shared__ __align__(16) short Bs[2][4096];
    const int t = threadIdx.x;
    const int lane = t & 63, wv = t >> 6;

    const int nwg = gridDim.x;
    int bid = blockIdx.x;
    int qq = nwg >> 3, rr = nwg & 7;
    int xcd = bid & 7, ii = bid >> 3;
    int v = (xcd < rr ? xcd * (qq + 1) : rr * (qq + 1) + (xcd - rr) * qq) + ii;
    const int tiles = nwg / nSplit;
    const int kr = v / tiles, rem = v % tiles;
    const int m0 = (rem % nMB) * 64, n0 = (rem / nMB) * 64;
    const int KS = K / nSplit;
    const int kb = kr * KS;

    const int wm = (wv >> 1) * 32, wn = (wv & 1) * 32;
    const int q4 = lane >> 4, l16 = lane & 15;

    f32x4 zero4 = {0.f, 0.f, 0.f, 0.f};
    f32x4 acc[2][2];
#pragma unroll
    for (int i = 0; i < 2; i++)
#pragma unroll
        for (int j = 0; j < 2; j++) acc[i][j] = zero4;

    auto stage = [&](int buf, int k0) {
#pragma unroll
        for (int i = 0; i < 2; i++) {
            int g = i * 256 + t;            // granule 0..511
            int q = g >> 6, r = g & 63;     // q = k-octet 0..7, r = row 0..63
            gl2lds16(A + (size_t)(m0 + r) * K + kb + k0 + q * 8, &As[buf][g * 8]);
        }
#pragma unroll
        for (int i = 0; i < 2; i++) {
            int g = i * 256 + t;
            int q = g >> 6, r = g & 63;
            int gr = n0 + r; if (gr > N - 1) gr = N - 1;
            gl2lds16(B + (size_t)gr * K + kb + k0 + q * 8, &Bs[buf][g * 8]);
        }
    };

    const int NT = KS >> 6;
    stage(0, 0);
    for (int tt = 0; tt < NT; tt++) {
        const int cur = tt & 1;
        if (tt + 1 < NT) {
            stage(cur ^ 1, (tt + 1) << 6);
            asm volatile("s_waitcnt vmcnt(4)" ::: "memory");
        } else {
            asm volatile("s_waitcnt vmcnt(0)" ::: "memory");
        }
        __builtin_amdgcn_s_barrier();

        short8 af[2][2], bf[2][2];
#pragma unroll
        for (int kk = 0; kk < 2; kk++) {
#pragma unroll
            for (int mt = 0; mt < 2; mt++)
                af[kk][mt] = *(const short8*)(&As[cur][(kk * 4 + q4) * 512 + (wm + mt * 16 + l16) * 8]);
#pragma unroll
            for (int nt = 0; nt < 2; nt++)
                bf[kk][nt] = *(const short8*)(&Bs[cur][(kk * 4 + q4) * 512 + (wn + nt * 16 + l16) * 8]);
        }
        asm volatile("s_waitcnt lgkmcnt(0)" ::: "memory");
        __builtin_amdgcn_s_barrier();

#pragma unroll
        for (int kk = 0; kk < 2; kk++)
#pragma unroll
            for (int mt = 0; mt < 2; mt++)
#pragma unroll
                for (int nt = 0; nt < 2; nt++)
                    acc[mt][nt] = __builtin_amdgcn_mfma_f32_16x16x32_bf16(af[kk][mt], bf[kk][nt], acc[mt][nt], 0, 0, 0);
    }

#pragma unroll
    for (int mt = 0; mt < 2; mt++) {
        int row = m0 + wm + mt * 16 + (lane >> 4) * 4;
#pragma unroll
        for (int nt = 0; nt < 2; nt++) {
            int col = n0 + wn + nt * 16 + l16;
            if (col < N) {
#pragma unroll
                for (int r = 0; r < 4; r++) {
                    size_t o = (size_t)(row + r) * N + col;
                    float val = acc[mt][nt][r];
                    if (nSplit > 1) atomicAdd(&C[o], val);
                    else if (addflag) C[o] += val;
                    else C[o] = val;
                }
            }
        }
    }
}

// ---------------- GEMM v1 (fallback, fp32 B): kept from round 1 ----------------
#define LDSK 56
__global__ __launch_bounds__(256) void gemm_bt_k(const short* __restrict__ A,
                                                 const float* __restrict__ B,
                                                 float* __restrict__ C,
                                                 int N, int K, int addflag) {
    __shared__ __align__(16) short As[128 * LDSK];
    __shared__ __align__(16) short Bs[128 * LDSK];
    const int t = threadIdx.x;
    const int lane = t & 63, wv = t >> 6;
    const int m0 = blockIdx.x * 128, n0 = blockIdx.y * 128;
    const int wm = (wv >> 1) * 64, wn = (wv & 1) * 64;
    f32x4 zero4 = {0.f, 0.f, 0.f, 0.f};
    f32x4 acc[4][4];
#pragma unroll
    for (int i = 0; i < 4; i++)
#pragma unroll
        for (int j = 0; j < 4; j++) acc[i][j] = zero4;
    for (int k0 = 0; k0 < K; k0 += 32) {
        uint4  av[2];
        float4 bv[4];
#pragma unroll
        for (int i = 0; i < 2; i++) {
            int c = i * 256 + t, row = c >> 2, kc = c & 3;
            av[i] = *(const uint4*)(A + (size_t)(m0 + row) * K + k0 + kc * 8);
        }
#pragma unroll
        for (int i = 0; i < 4; i++) {
            int c = i * 256 + t, row = c >> 3, kc = c & 7;
            int gr = n0 + row; if (gr > N - 1) gr = N - 1;
            bv[i] = *(const float4*)(B + (size_t)gr * K + k0 + kc * 4);
        }
        __syncthreads();
#pragma unroll
        for (int i = 0; i < 2; i++) {
            int c = i * 256 + t, row = c >> 2, kc = c & 3;
            *(uint4*)(As + row * LDSK + kc * 8) = av[i];
        }
#pragma unroll
        for (int i = 0; i < 4; i++) {
            int c = i * 256 + t, row = c >> 3, kc = c & 7;
            short4v sv;
            sv.x = f2bf(bv[i].x); sv.y = f2bf(bv[i].y);
            sv.z = f2bf(bv[i].z); sv.w = f2bf(bv[i].w);
            *(short4v*)(Bs + row * LDSK + kc * 4) = sv;
        }
        __syncthreads();
        short8 af[4], bf[4];
#pragma unroll
        for (int mt = 0; mt < 4; mt++)
            af[mt] = *(const short8*)(As + (wm + mt * 16 + (lane & 15)) * LDSK + (lane >> 4) * 8);
#pragma unroll
        for (int nt = 0; nt < 4; nt++)
            bf[nt] = *(const short8*)(Bs + (wn + nt * 16 + (lane & 15)) * LDSK + (lane >> 4) * 8);
#pragma unroll
        for (int mt = 0; mt < 4; mt++)
#pragma unroll
            for (int nt = 0; nt < 4; nt++)
                acc[mt][nt] = __builtin_amdgcn_mfma_f32_16x16x32_bf16(af[mt], bf[nt], acc[mt][nt], 0, 0, 0);
    }
#pragma unroll
    for (int mt = 0; mt < 4; mt++) {
        int row = m0 + wm + mt * 16 + (lane >> 4) * 4;
#pragma unroll
        for (int nt = 0; nt < 4; nt++) {
            int col = n0 + wn + nt * 16 + (lane & 15);
            if (col < N) {
#pragma unroll
                for (int r = 0; r < 4; r++) {
                    size_t o = (size_t)(row + r) * N + col;
                    float val = acc[mt][nt][r];
                    if (addflag) C[o] += val; else C[o] = val;
                }
            }
        }
    }
}

// -------- fused depthwise causal conv (win 4) + bias + SiLU, and dt/dA ----------
__global__ void convdt_k(const float* __restrict__ zx, const float* __restrict__ cw,
                         const float* __restrict__ cb, const float* __restrict__ dt_bias,
                         const float* __restrict__ A_log, float* __restrict__ xbc,
                         float* __restrict__ dts, float* __restrict__ dAv) {
    int c = blockIdx.x * 256 + threadIdx.x;
    int t = blockIdx.y;
    if (c < CONVDIM) {
        float acc = cb[c];
#pragma unroll
        for (int j = 0; j < 4; j++) {
            int ts = t - 3 + j;
            if (ts >= 0) acc += cw[c * 4 + j] * zx[(size_t)ts * DINPROJ + DINNER + c];
        }
        xbc[(size_t)t * CONVDIM + c] = acc / (1.f + __expf(-acc));
    } else if (c < CONVDIM + NHEADS) {
        int h = c - CONVDIM;
        float d = zx[(size_t)t * DINPROJ + 3200 + h] + dt_bias[h];
        float sp = (d > 20.f) ? d : log1pf(__expf(d));
        dts[t * NHEADS + h] = sp;
        dAv[t * NHEADS + h] = __expf(-__expf(A_log[h]) * sp);
    }
}

// ---------------- sequential SSM scan v4 ----------------
// 192 blocks (24 heads x 8 p-groups of 8), 512 threads (8 waves, 2 waves/SIMD).
// n-split x4: wave pair (wv>>1) owns 16 n; 1 recurrence state/lane.
__global__ __launch_bounds__(512) void scan_k(const float* __restrict__ xbc,
                                              const float* __restrict__ dts,
                                              const float* __restrict__ dAv,
                                              float* __restrict__ yraw) {
    __shared__ __align__(16) float BCs[64][128];
    __shared__ __align__(16) float xs[64][8];
    __shared__ float dash[64];
    __shared__ float ys[64][8][4];
    int h = blockIdx.x >> 3;
    int pbase = (blockIdx.x & 7) * 8;
    int t = threadIdx.x, lane = t & 63, wv = t >> 6;
    int nq = wv >> 1;                      // n-quarter 0..3
    int pl = (wv & 1) * 4 + (lane >> 4);   // 0..7
    int n4 = lane & 15;
    int nbase = nq * 16;
    float s0 = 0.f;

    for (int tc = 0; tc < 16; tc++) {
        __syncthreads();
#pragma unroll 4
        for (int it = 0; it < 4; it++) {
            int idx = it * 512 + t;
            int trow = idx >> 5, c4 = idx & 31;
            *(float4*)&BCs[trow][c4 * 4] =
                *(const float4*)(xbc + (size_t)(tc * 64 + trow) * CONVDIM + DINNER + c4 * 4);
        }
        if (t < 128) {
            int trow = t >> 1, hf = t & 1;
            float dtv = dts[(tc * 64 + trow) * NHEADS + h];
            float4 xv = *(const float4*)(xbc + (size_t)(tc * 64 + trow) * CONVDIM
                                         + h * HEADDIM + pbase + hf * 4);
            xv.x *= dtv; xv.y *= dtv; xv.z *= dtv; xv.w *= dtv;
            *(float4*)&xs[trow][hf * 4] = xv;
        }
        if (t < 64) dash[t] = dAv[(tc * 64 + t) * NHEADS + h];
        __syncthreads();

#pragma unroll 4
        for (int tt = 0; tt < 64; tt++) {
            float Bv = BCs[tt][nbase + n4];
            float Cv = BCs[tt][64 + nbase + n4];
            float dtx = xs[tt][pl];
            float da = dash[tt];
            s0 = fmaf(da, s0, dtx * Bv);
            float part = s0 * Cv;
            part = dppadd<0xB1>(part);    // quad_perm [1,0,3,2]  (xor 1)
            part = dppadd<0x4E>(part);    // quad_perm [2,3,0,1]  (xor 2)
            part = dppadd<0x114>(part);   // row_shr:4
            part = dppadd<0x118>(part);   // row_shr:8
            if (n4 == 0) ys[tt][pl][nq] = part;
        }
        __syncthreads();
        {
            int tt2 = t >> 3, pl2 = t & 7;
            float yv = ys[tt2][pl2][0] + ys[tt2][pl2][1] + ys[tt2][pl2][2] + ys[tt2][pl2][3];
            yraw[(size_t)(tc * 64 + tt2) * DINNER + h * HEADDIM + pbase + pl2] = yv;
        }
    }
}

// ---------------- (y + Dp*xh) * silu(z), RMS norm, * rms_w -> bf16 ----------------
__global__ void rms_k(const float* __restrict__ yraw, const float* __restrict__ zx,
                      const float* __restrict__ xbc, const float* __restrict__ Dp,
                      const float* __restrict__ rw, short* __restrict__ yn) {
    int row = blockIdx.x, t = threadIdx.x;
    float v[6];
    float q = 0.f;
#pragma unroll
    for (int j = 0; j < 6; j++) {
        int i = t + j * 256;
        float z  = zx[(size_t)row * DINPROJ + i];
        float xh = xbc[(size_t)row * CONVDIM + i];
        float y  = yraw[(size_t)row * DINNER + i] + Dp[i >> 6] * xh;
        float val = y * (z / (1.f + __expf(-z)));
        v[j] = val;
        q += val * val;
    }
    __shared__ float sb[4];
    for (int off = 32; off; off >>= 1) q += __shfl_down(q, off);
    if (!(t & 63)) sb[t >> 6] = q;
    __syncthreads();
    q = sb[0] + sb[1] + sb[2] + sb[3];
    float rs = rsqrtf(q * (1.f / DINNER) + 1e-5f);
#pragma unroll
    for (int j = 0; j < 6; j++) {
        int i = t + j * 256;
        yn[(size_t)row * DINNER + i] = f2bf(v[j] * rs * rw[i]);
    }
}

// ---------------- per-row online logsumexp + NLL (fallback path) ----------------
__global__ void loss_row_k(const float* __restrict__ logits, const int* __restrict__ tg,
                           float* __restrict__ lossp) {
    int r = blockIdx.x, t = threadIdx.x;
    const float* lr = logits + (size_t)r * VOCABN;
    float m = -3.0e38f, s = 0.f;
    for (int j = t; j < VOCABN; j += 256) {
        float v = lr[j];
        if (v > m) { s = s * __expf(m - v) + 1.f; m = v; }
        else s += __expf(v - m);
    }
    for (int off = 32; off; off >>= 1) {
        float mo = __shfl_down(m, off), so = __shfl_down(s, off);
        float nm = fmaxf(m, mo);
        s = s * __expf(m - nm) + so * __expf(mo - nm);
        m = nm;
    }
    __shared__ float sm[4], ss[4];
    if (!(t & 63)) { sm[t >> 6] = m; ss[t >> 6] = s; }
    __syncthreads();
    if (t == 0) {
        m = sm[0]; s = ss[0];
        for (int w = 1; w < 4; w++) {
            float nm = fmaxf(m, sm[w]);
            s = s * __expf(m - nm) + ss[w] * __expf(sm[w] - nm);
            m = nm;
        }
        lossp[r] = (m + logf(s)) - lr[tg[r]];
    }
}

// ---------------- combine per-panel (m,s) partials -> per-row NLL ----------------
__global__ void loss_fin2_k(const float2* __restrict__ P, const float* __restrict__ logits,
                            const int* __restrict__ tg, float* __restrict__ lossp) {
    int r = blockIdx.x * 256 + threadIdx.x;
    float m = -3.0e38f;
    for (int p = 0; p < 197; p++)
        m = fmaxf(m, P[(size_t)p * 1024 + r].x);
    float s = 0.f;
    for (int p = 0; p < 197; p++) {
        float2 q = P[(size_t)p * 1024 + r];
        s += q.y * __expf(q.x - m);
    }
    lossp[r] = (m + logf(s)) - logits[(size_t)r * VOCABN + tg[r]];
}

__global__ void loss_fin_k(const float* __restrict__ lossp, float* __restrict__ out) {
    int t = threadIdx.x;
    float s = lossp[t] + lossp[t + 256] + lossp[t + 512] + lossp[t + 768];
    for (int off = 32; off; off >>= 1) s += __shfl_down(s, off);
    __shared__ float sb[4];
    if (!(t & 63)) sb[t >> 6] = s;
    __syncthreads();
    if (t == 0) out[(size_t)SL * VOCABN] = (sb[0] + sb[1] + sb[2] + sb[3]) * (1.f / SL);
}

// ---------------- driver ----------------
extern "C" void kernel_launch(void* const* d_in, const int* in_sizes, int n_in,
                              void* d_out, int out_size, void* d_ws, size_t ws_size,
                              hipStream_t stream) {
    const int*   idx     = (const int*)d_in[0];
    const int*   targets = (const int*)d_in[1];
    const float* emb     = (const float*)d_in[2];
    const float* ln_w    = (const float*)d_in[3];
    const float* ln_b    = (const float*)d_in[4];
    const float* W_in    = (const float*)d_in[5];
    const float* conv_w  = (const float*)d_in[6];
    const float* conv_b  = (const float*)d_in[7];
    const float* dt_bias = (const float*)d_in[8];
    const float* A_log   = (const float*)d_in[9];
    const float* Dp      = (const float*)d_in[10];
    const float* rms_w   = (const float*)d_in[11];
    const float* W_out   = (const float*)d_in[12];
    const float* lnf_w   = (const float*)d_in[13];
    const float* lnf_b   = (const float*)d_in[14];

    char* ws = (char*)d_ws;
    float* x     = (float*)(ws + 0);
    short* xn    = (short*)(ws + 3145728);
    float* zx    = (float*)(ws + 4718592);
    float* xbc   = (float*)(ws + 17924096);
    float* dts   = (float*)(ws + 24739840);
    float* dAv   = (float*)(ws + 24838144);
    float* yraw  = (float*)(ws + 24936448);
    short* yn    = (short*)(ws + 31227904);
    float* lossp = (float*)(ws + 34373632);
    short* wInb  = (short*)(ws + 34377728);   // 19,806,208 B
    short* wOutb = (short*)(ws + 54183936);   //  9,437,184 B
    short* embb  = (short*)(ws + 63621120);   // 77,194,752 B
    float2* pms  = (float2*)(ws + 4718592);   // reuse zx space (dead at logits time)
    float* logits = (float*)d_out;

    const bool big = ws_size >= 140815872ull;

    if (big) {
        int nWin  = NLAYER * DINPROJ * DMODEL;   // 9,903,104
        int nWout = NLAYER * DMODEL * DINNER;    // 4,718,592
        int nEmb  = VOCABN * DMODEL;             // 38,597,376
        cvt_k<<<(nWin / 4 + 255) / 256, 256, 0, stream>>>(W_in, wInb, nWin);
        cvt_k<<<(nWout / 4 + 255) / 256, 256, 0, stream>>>(W_out, wOutb, nWout);
        cvt_k<<<(nEmb / 4 + 255) / 256, 256, 0, stream>>>(emb, embb, nEmb);
    }

    embed_k<<<dim3(3, SL), 256, 0, stream>>>(idx, emb, x);
    for (int l = 0; l < NLAYER; l++) {
        ln_k<<<SL, 256, 0, stream>>>(x, ln_w + l * DMODEL, ln_b + l * DMODEL, xn);
        if (big) {
            // zero zx (1024 x 3224 fp32 = 825,344 float4) then split-K x2 atomic GEMM
            zero_k<<<3224, 256, 0, stream>>>(zx, 825344);
            gemm128_k<<<416, 256, 0, stream>>>(xn, wInb + (size_t)l * DINPROJ * DMODEL,
                                               zx, DINPROJ, DMODEL, 0, 8, 2);
        } else {
            gemm_bt_k<<<dim3(8, 26), 256, 0, stream>>>(xn, W_in + (size_t)l * DINPROJ * DMODEL,
                                                       zx, DINPROJ, DMODEL, 0);
        }
        convdt_k<<<dim3(7, SL), 256, 0, stream>>>(zx, conv_w + l * CONVDIM * 4,
                                                  conv_b + l * CONVDIM,
                                                  dt_bias + l * NHEADS, A_log + l * NHEADS,
                                                  xbc, dts, dAv);
        scan_k<<<192, 512, 0, stream>>>(xbc, dts, dAv, yraw);
        rms_k<<<SL, 256, 0, stream>>>(yraw, zx, xbc, Dp + l * NHEADS, rms_w + l * DINNER, yn);
        if (big)
            gemm64_k<<<768, 256, 0, stream>>>(yn, wOutb + (size_t)l * DMODEL * DINNER,
                                              x, DMODEL, DINNER, 1, 16, 4);
        else
            gemm_bt_k<<<dim3(8, 6), 256, 0, stream>>>(yn, W_out + (size_t)l * DMODEL * DINNER,
                                                      x, DMODEL, DINNER, 1);
    }
    ln_k<<<SL, 256, 0, stream>>>(x, lnf_w, lnf_b, xn);
    if (big) {
        gemm_bb_k<<<4 * 197, 512, 0, stream>>>(xn, embb, logits, pms, VOCABN, DMODEL, 0);
        loss_fin2_k<<<4, 256, 0, stream>>>(pms, logits, targets, lossp);
    } else {
        gemm_bt_k<<<dim3(8, 393), 256, 0, stream>>>(xn, emb, logits, VOCABN, DMODEL, 0);
        loss_row_k<<<SL, 256, 0, stream>>>(logits, targets, lossp);
    }
    loss_fin_k<<<1, 256, 0, stream>>>(lossp, logits);
}

// Round 13
// 1006.947 us; speedup vs baseline: 1.1206x; 1.1206x over previous
//
#include <hip/hip_runtime.h>
#include <hip/hip_bf16.h>
#include <math.h>

#define SL     1024
#define DMODEL 768
#define NLAYER 4
#define NSTATE 64
#define HEADDIM 64
#define DINNER 1536
#define NHEADS 24
#define CONVDIM 1664
#define DINPROJ 3224
#define VOCABN 50257

typedef __attribute__((ext_vector_type(8))) short short8;
typedef __attribute__((ext_vector_type(4))) short short4v;
typedef __attribute__((ext_vector_type(4))) float f32x4;

__device__ __forceinline__ short f2bf(float f) {
    unsigned int u = __builtin_bit_cast(unsigned int, f);
    u += 0x7fffu + ((u >> 16) & 1u);
    return (short)(u >> 16);
}

#define AS1 __attribute__((address_space(1)))
#define AS3 __attribute__((address_space(3)))
__device__ __forceinline__ void gl2lds16(const void* g, void* l) {
    __builtin_amdgcn_global_load_lds((const AS1 unsigned int*)g,
                                     (AS3 unsigned int*)(unsigned int)(uintptr_t)l,
                                     16, 0, 0);
}

template <int CTRL>
__device__ __forceinline__ float dppadd(float x) {
    int v = __builtin_amdgcn_update_dpp(0, __builtin_bit_cast(int, x), CTRL, 0xf, 0xf, true);
    return x + __builtin_bit_cast(float, v);
}

// ---------------- fp32 -> bf16 bulk convert ----------------
__global__ void cvt_k(const float* __restrict__ s, short* __restrict__ d, int n) {
    int i = (blockIdx.x * 256 + threadIdx.x) * 4;
    if (i >= n) return;
    float4 v = *(const float4*)(s + i);
    short4v o;
    o.x = f2bf(v.x); o.y = f2bf(v.y); o.z = f2bf(v.z); o.w = f2bf(v.w);
    *(short4v*)(d + i) = o;
}

// ---------------- embedding gather ----------------
__global__ void embed_k(const int* __restrict__ idx, const float* __restrict__ emb,
                        float* __restrict__ x) {
    int d = blockIdx.x * 256 + threadIdx.x;
    int t = blockIdx.y;
    x[t * DMODEL + d] = emb[(size_t)idx[t] * DMODEL + d];
}

// ---------------- layernorm (768), out bf16 ----------------
__global__ void ln_k(const float* __restrict__ x, const float* __restrict__ w,
                     const float* __restrict__ b, short* __restrict__ out) {
    int row = blockIdx.x, t = threadIdx.x;
    const float* xr = x + row * DMODEL;
    float v0 = xr[t], v1 = xr[t + 256], v2 = xr[t + 512];
    float s = v0 + v1 + v2;
    float q = v0 * v0 + v1 * v1 + v2 * v2;
    __shared__ float sa[4], sb[4];
    for (int off = 32; off; off >>= 1) { s += __shfl_down(s, off); q += __shfl_down(q, off); }
    if (!(t & 63)) { sa[t >> 6] = s; sb[t >> 6] = q; }
    __syncthreads();
    s = sa[0] + sa[1] + sa[2] + sa[3];
    q = sb[0] + sb[1] + sb[2] + sb[3];
    float mean = s * (1.f / DMODEL);
    float var  = q * (1.f / DMODEL) - mean * mean;
    float rs = rsqrtf(var + 1e-5f);
    out[row * DMODEL + t      ] = f2bf((v0 - mean) * rs * w[t      ] + b[t      ]);
    out[row * DMODEL + t + 256] = f2bf((v1 - mean) * rs * w[t + 256] + b[t + 256]);
    out[row * DMODEL + t + 512] = f2bf((v2 - mean) * rs * w[t + 512] + b[t + 512]);
}

// ---------------- GEMM v9 (logits): C[m,n] = sum_k A_bf16[m,k] * B_bf16[n,k] ------
// (round-8 best: 235 us, frozen) 256x256 tile, BK=64, 512 threads (8 waves, 2m x 4n).
// 4-phase schedule with counted vmcnt(4); vmcnt(0) only in final tile tail.
// LDS [buf][kk (2)][q (4)][row (256)][8 shorts]. Fused NLL epilogue (two-pass).
__global__ __launch_bounds__(512) void gemm_bb_k(const short* __restrict__ A,
                                                 const short* __restrict__ B,
                                                 float* __restrict__ C,
                                                 float2* __restrict__ P,
                                                 int N, int K, int addflag) {
    __shared__ __align__(16) short As[2][16384];  // [buf][kk*8192 + q*2048 + row*8]
    __shared__ __align__(16) short Bs[2][16384];
    const int t = threadIdx.x;
    const int lane = t & 63, wv = t >> 6;

    const int nwg = gridDim.x;
    int bid = blockIdx.x;
    int qq = nwg >> 3, rr = nwg & 7;
    int xcd = bid & 7, ii = bid >> 3;
    int v = (xcd < rr ? xcd * (qq + 1) : rr * (qq + 1) + (xcd - rr) * qq) + ii;
    const int m0 = (v & 3) * 256;          // 4 m-blocks (M = 1024)
    const int n0 = (v >> 2) * 256;

    const int wm = (wv >> 2) * 128, wn = (wv & 3) * 64;
    const int q4 = lane >> 4, l16 = lane & 15;

    f32x4 zero4 = {0.f, 0.f, 0.f, 0.f};
    f32x4 acc[8][4];
#pragma unroll
    for (int i = 0; i < 8; i++)
#pragma unroll
        for (int j = 0; j < 4; j++) acc[i][j] = zero4;

    auto stageA = [&](int buf, int kh, int k0) {
#pragma unroll
        for (int i = 0; i < 2; i++) {
            int g = i * 512 + t;            // 0..1023
            int q = g >> 8, r = g & 255;
            gl2lds16(A + (size_t)(m0 + r) * K + k0 + kh * 32 + q * 8,
                     &As[buf][kh * 8192 + g * 8]);
        }
    };
    auto stageB = [&](int buf, int kh, int k0) {
#pragma unroll
        for (int i = 0; i < 2; i++) {
            int g = i * 512 + t;
            int q = g >> 8, r = g & 255;
            int gr = n0 + r; if (gr > N - 1) gr = N - 1;
            gl2lds16(B + (size_t)gr * K + k0 + kh * 32 + q * 8,
                     &Bs[buf][kh * 8192 + g * 8]);
        }
    };

    const int NT = K >> 6;                 // BK = 64 (NT = 12)
    stageA(0, 0, 0); stageB(0, 0, 0); stageA(0, 1, 0); stageB(0, 1, 0);
    asm volatile("s_waitcnt vmcnt(4)" ::: "memory");
    __builtin_amdgcn_s_barrier();

    for (int tt = 0; tt < NT; tt++) {
        const int cur = tt & 1;
        const bool pf = (tt + 1 < NT);
        const int k1 = (tt + 1) << 6;
        const short* Ac = &As[cur][0];
        const short* Bc = &Bs[cur][0];

        short8 bfk[4];
        // ---- phase 0: kk=0, mt 0..3 ; stage AK0(t+1) ----
        {
            short8 af[4];
#pragma unroll
            for (int nt = 0; nt < 4; nt++)
                bfk[nt] = *(const short8*)(Bc + q4 * 2048 + (wn + nt * 16 + l16) * 8);
#pragma unroll
            for (int mt = 0; mt < 4; mt++)
                af[mt] = *(const short8*)(Ac + q4 * 2048 + (wm + mt * 16 + l16) * 8);
            if (pf) stageA(cur ^ 1, 0, k1);
            __builtin_amdgcn_s_barrier();
            __builtin_amdgcn_s_setprio(1);
#pragma unroll
            for (int mt = 0; mt < 4; mt++)
#pragma unroll
                for (int nt = 0; nt < 4; nt++)
                    acc[mt][nt] = __builtin_amdgcn_mfma_f32_16x16x32_bf16(af[mt], bfk[nt], acc[mt][nt], 0, 0, 0);
            __builtin_amdgcn_s_setprio(0);
            __builtin_amdgcn_s_barrier();
        }
        // ---- phase 1: kk=0, mt 4..7 ; stage BK0(t+1) ; wait K-half1 ----
        {
            short8 af[4];
#pragma unroll
            for (int mt = 0; mt < 4; mt++)
                af[mt] = *(const short8*)(Ac + q4 * 2048 + (wm + (mt + 4) * 16 + l16) * 8);
            if (pf) stageB(cur ^ 1, 0, k1);
            __builtin_amdgcn_s_barrier();
            __builtin_amdgcn_s_setprio(1);
#pragma unroll
            for (int mt = 0; mt < 4; mt++)
#pragma unroll
                for (int nt = 0; nt < 4; nt++)
                    acc[mt + 4][nt] = __builtin_amdgcn_mfma_f32_16x16x32_bf16(af[mt], bfk[nt], acc[mt + 4][nt], 0, 0, 0);
            __builtin_amdgcn_s_setprio(0);
            if (pf) asm volatile("s_waitcnt vmcnt(4)" ::: "memory");
            else    asm volatile("s_waitcnt vmcnt(0)" ::: "memory");
            __builtin_amdgcn_s_barrier();
        }
        // ---- phase 2: kk=1, mt 0..3 ; stage AK1(t+1) ----
        {
            short8 af[4];
#pragma unroll
            for (int nt = 0; nt < 4; nt++)
                bfk[nt] = *(const short8*)(Bc + 8192 + q4 * 2048 + (wn + nt * 16 + l16) * 8);
#pragma unroll
            for (int mt = 0; mt < 4; mt++)
                af[mt] = *(const short8*)(Ac + 8192 + q4 * 2048 + (wm + mt * 16 + l16) * 8);
            if (pf) stageA(cur ^ 1, 1, k1);
            __builtin_amdgcn_s_barrier();
            __builtin_amdgcn_s_setprio(1);
#pragma unroll
            for (int mt = 0; mt < 4; mt++)
#pragma unroll
                for (int nt = 0; nt < 4; nt++)
                    acc[mt][nt] = __builtin_amdgcn_mfma_f32_16x16x32_bf16(af[mt], bfk[nt], acc[mt][nt], 0, 0, 0);
            __builtin_amdgcn_s_setprio(0);
            __builtin_amdgcn_s_barrier();
        }
        // ---- phase 3: kk=1, mt 4..7 ; stage BK1(t+1) ; wait next K-half0 ----
        {
            short8 af[4];
#pragma unroll
            for (int mt = 0; mt < 4; mt++)
                af[mt] = *(const short8*)(Ac + 8192 + q4 * 2048 + (wm + (mt + 4) * 16 + l16) * 8);
            if (pf) stageB(cur ^ 1, 1, k1);
            __builtin_amdgcn_s_barrier();
            __builtin_amdgcn_s_setprio(1);
#pragma unroll
            for (int mt = 0; mt < 4; mt++)
#pragma unroll
                for (int nt = 0; nt < 4; nt++)
                    acc[mt + 4][nt] = __builtin_amdgcn_mfma_f32_16x16x32_bf16(af[mt], bfk[nt], acc[mt + 4][nt], 0, 0, 0);
            __builtin_amdgcn_s_setprio(0);
            if (pf) asm volatile("s_waitcnt vmcnt(4)" ::: "memory");
            else    asm volatile("s_waitcnt vmcnt(0)" ::: "memory");
            __builtin_amdgcn_s_barrier();
        }
    }

    // ---- C store ----
#pragma unroll
    for (int mt = 0; mt < 8; mt++) {
        int row = m0 + wm + mt * 16 + q4 * 4;
#pragma unroll
        for (int nt = 0; nt < 4; nt++) {
            int col = n0 + wn + nt * 16 + l16;
            if (col < N) {
#pragma unroll
                for (int r = 0; r < 4; r++) {
                    size_t o = (size_t)(row + r) * N + col;
                    float val = acc[mt][nt][r];
                    if (addflag) C[o] += val; else C[o] = val;
                }
            }
        }
    }

    // ---- fused per-row logsumexp partial (two-pass: max, then sum-exp) ----
    float2* lds_ms = (float2*)&As[0][0];   // [256 rows][stride 5], 10 KB (padded)
    const int nw = wv & 3;
#pragma unroll
    for (int mt = 0; mt < 8; mt++) {
#pragma unroll
        for (int r = 0; r < 4; r++) {
            float m = -3.0e38f;
#pragma unroll
            for (int nt = 0; nt < 4; nt++) {
                int col = n0 + wn + nt * 16 + l16;
                if (col < N) m = fmaxf(m, acc[mt][nt][r]);
            }
#pragma unroll
            for (int off = 1; off < 16; off <<= 1)
                m = fmaxf(m, __shfl_xor(m, off));
            float s = 0.f;
#pragma unroll
            for (int nt = 0; nt < 4; nt++) {
                int col = n0 + wn + nt * 16 + l16;
                if (col < N) s += __expf(acc[mt][nt][r] - m);
            }
#pragma unroll
            for (int off = 1; off < 16; off <<= 1)
                s += __shfl_xor(s, off);
            if (l16 == 0)
                lds_ms[(wm + mt * 16 + q4 * 4 + r) * 5 + nw] = make_float2(m, s);
        }
    }
    __syncthreads();
    if (t < 256) {
        float m = -3.0e38f, s = 0.f;
#pragma unroll
        for (int w = 0; w < 4; w++) {
            float2 p = lds_ms[t * 5 + w];
            float nm = fmaxf(m, p.x);
            s = s * __expf(m - nm) + p.y * __expf(p.x - nm);
            m = nm;
        }
        P[(size_t)(v >> 2) * 1024 + (m0 + t)] = make_float2(m, s);
    }
}

// ---------------- GEMM v2 (128-tile, 2-phase) ------------------------------------
// BM=BN=128, BK=32, 256 threads, wave tile 64x64 (4x4 of 16x16x32 MFMA).
// Counted vmcnt(4). 1-D grid (div by 8) + bijective XCD swizzle, m fastest.
__global__ __launch_bounds__(256) void gemm128_k(const short* __restrict__ A,
                                                 const short* __restrict__ B,
                                                 float* __restrict__ C,
                                                 int N, int K, int addflag, int nMB) {
    __shared__ __align__(16) short As[2][4096];  // per buf: 4 q * 128 r * 8 = 8 KB
    __shared__ __align__(16) short Bs[2][4096];
    const int t = threadIdx.x;
    const int lane = t & 63, wv = t >> 6;

    const int nwg = gridDim.x;
    int bid = blockIdx.x;
    int qq = nwg >> 3, rr = nwg & 7;
    int xcd = bid & 7, ii = bid >> 3;
    int v = (xcd < rr ? xcd * (qq + 1) : rr * (qq + 1) + (xcd - rr) * qq) + ii;
    const int m0 = (v % nMB) * 128, n0 = (v / nMB) * 128;

    const int wm = (wv >> 1) * 64, wn = (wv & 1) * 64;
    const int q4 = lane >> 4, l16 = lane & 15;

    f32x4 zero4 = {0.f, 0.f, 0.f, 0.f};
    f32x4 acc[4][4];
#pragma unroll
    for (int i = 0; i < 4; i++)
#pragma unroll
        for (int j = 0; j < 4; j++) acc[i][j] = zero4;

    auto stage = [&](int buf, int k0) {
#pragma unroll
        for (int i = 0; i < 2; i++) {
            int g = i * 256 + t;            // granule 0..511
            int q = g >> 7, r = g & 127;
            gl2lds16(A + (size_t)(m0 + r) * K + k0 + q * 8, &As[buf][g * 8]);
        }
#pragma unroll
        for (int i = 0; i < 2; i++) {
            int g = i * 256 + t;
            int q = g >> 7, r = g & 127;
            int gr = n0 + r; if (gr > N - 1) gr = N - 1;
            gl2lds16(B + (size_t)gr * K + k0 + q * 8, &Bs[buf][g * 8]);
        }
    };

    const int NT = K >> 5;
    stage(0, 0);
    for (int tt = 0; tt < NT; tt++) {
        const int cur = tt & 1;
        if (tt + 1 < NT) {
            stage(cur ^ 1, (tt + 1) << 5);
            asm volatile("s_waitcnt vmcnt(4)" ::: "memory");
        } else {
            asm volatile("s_waitcnt vmcnt(0)" ::: "memory");
        }
        __builtin_amdgcn_s_barrier();

        short8 af[4], bf[4];
#pragma unroll
        for (int mt = 0; mt < 4; mt++)
            af[mt] = *(const short8*)(&As[cur][q4 * 1024 + (wm + mt * 16 + l16) * 8]);
#pragma unroll
        for (int nt = 0; nt < 4; nt++)
            bf[nt] = *(const short8*)(&Bs[cur][q4 * 1024 + (wn + nt * 16 + l16) * 8]);
        asm volatile("s_waitcnt lgkmcnt(0)" ::: "memory");
        __builtin_amdgcn_s_barrier();

#pragma unroll
        for (int mt = 0; mt < 4; mt++)
#pragma unroll
            for (int nt = 0; nt < 4; nt++)
                acc[mt][nt] = __builtin_amdgcn_mfma_f32_16x16x32_bf16(af[mt], bf[nt], acc[mt][nt], 0, 0, 0);
    }

#pragma unroll
    for (int mt = 0; mt < 4; mt++) {
        int row = m0 + wm + mt * 16 + (lane >> 4) * 4;
#pragma unroll
        for (int nt = 0; nt < 4; nt++) {
            int col = n0 + wn + nt * 16 + l16;
            if (col < N) {
#pragma unroll
                for (int r = 0; r < 4; r++) {
                    size_t o = (size_t)(row + r) * N + col;
                    float val = acc[mt][nt][r];
                    if (addflag) C[o] += val; else C[o] = val;
                }
            }
        }
    }
}

// ---------------- GEMM v3 (64-tile, 2-phase) -------------------------------------
// BM=BN=64, BK=64, 256 threads, wave tile 32x32 (2x2 of 16x16x32 MFMA).
__global__ __launch_bounds__(256) void gemm64_k(const short* __restrict__ A,
                                                const short* __restrict__ B,
                                                float* __restrict__ C,
                                                int N, int K, int addflag, int nMB) {
    __shared__ __align__(16) short As[2][4096];  // per buf: 8 q * 64 r * 8
    __shared__ __align__(16) short Bs[2][4096];
    const int t = threadIdx.x;
    const int lane = t & 63, wv = t >> 6;

    const int nwg = gridDim.x;
    int bid = blockIdx.x;
    int qq = nwg >> 3, rr = nwg & 7;
    int xcd = bid & 7, ii = bid >> 3;
    int v = (xcd < rr ? xcd * (qq + 1) : rr * (qq + 1) + (xcd - rr) * qq) + ii;
    const int m0 = (v % nMB) * 64, n0 = (v / nMB) * 64;

    const int wm = (wv >> 1) * 32, wn = (wv & 1) * 32;
    const int q4 = lane >> 4, l16 = lane & 15;

    f32x4 zero4 = {0.f, 0.f, 0.f, 0.f};
    f32x4 acc[2][2];
#pragma unroll
    for (int i = 0; i < 2; i++)
#pragma unroll
        for (int j = 0; j < 2; j++) acc[i][j] = zero4;

    auto stage = [&](int buf, int k0) {
#pragma unroll
        for (int i = 0; i < 2; i++) {
            int g = i * 256 + t;            // granule 0..511
            int q = g >> 6, r = g & 63;     // q = k-octet 0..7, r = row 0..63
            gl2lds16(A + (size_t)(m0 + r) * K + k0 + q * 8, &As[buf][g * 8]);
        }
#pragma unroll
        for (int i = 0; i < 2; i++) {
            int g = i * 256 + t;
            int q = g >> 6, r = g & 63;
            int gr = n0 + r; if (gr > N - 1) gr = N - 1;
            gl2lds16(B + (size_t)gr * K + k0 + q * 8, &Bs[buf][g * 8]);
        }
    };

    const int NT = K >> 6;
    stage(0, 0);
    for (int tt = 0; tt < NT; tt++) {
        const int cur = tt & 1;
        if (tt + 1 < NT) {
            stage(cur ^ 1, (tt + 1) << 6);
            asm volatile("s_waitcnt vmcnt(4)" ::: "memory");
        } else {
            asm volatile("s_waitcnt vmcnt(0)" ::: "memory");
        }
        __builtin_amdgcn_s_barrier();

        short8 af[2][2], bf[2][2];
#pragma unroll
        for (int kk = 0; kk < 2; kk++) {
#pragma unroll
            for (int mt = 0; mt < 2; mt++)
                af[kk][mt] = *(const short8*)(&As[cur][(kk * 4 + q4) * 512 + (wm + mt * 16 + l16) * 8]);
#pragma unroll
            for (int nt = 0; nt < 2; nt++)
                bf[kk][nt] = *(const short8*)(&Bs[cur][(kk * 4 + q4) * 512 + (wn + nt * 16 + l16) * 8]);
        }
        asm volatile("s_waitcnt lgkmcnt(0)" ::: "memory");
        __builtin_amdgcn_s_barrier();

#pragma unroll
        for (int kk = 0; kk < 2; kk++)
#pragma unroll
            for (int mt = 0; mt < 2; mt++)
#pragma unroll
                for (int nt = 0; nt < 2; nt++)
                    acc[mt][nt] = __builtin_amdgcn_mfma_f32_16x16x32_bf16(af[kk][mt], bf[kk][nt], acc[mt][nt], 0, 0, 0);
    }

#pragma unroll
    for (int mt = 0; mt < 2; mt++) {
        int row = m0 + wm + mt * 16 + (lane >> 4) * 4;
#pragma unroll
        for (int nt = 0; nt < 2; nt++) {
            int col = n0 + wn + nt * 16 + l16;
            if (col < N) {
#pragma unroll
                for (int r = 0; r < 4; r++) {
                    size_t o = (size_t)(row + r) * N + col;
                    float val = acc[mt][nt][r];
                    if (addflag) C[o] += val; else C[o] = val;
                }
            }
        }
    }
}

// ---------------- GEMM v1 (fallback, fp32 B): kept from round 1 ----------------
#define LDSK 56
__global__ __launch_bounds__(256) void gemm_bt_k(const short* __restrict__ A,
                                                 const float* __restrict__ B,
                                                 float* __restrict__ C,
                                                 int N, int K, int addflag) {
    __shared__ __align__(16) short As[128 * LDSK];
    __shared__ __align__(16) short Bs[128 * LDSK];
    const int t = threadIdx.x;
    const int lane = t & 63, wv = t >> 6;
    const int m0 = blockIdx.x * 128, n0 = blockIdx.y * 128;
    const int wm = (wv >> 1) * 64, wn = (wv & 1) * 64;
    f32x4 zero4 = {0.f, 0.f, 0.f, 0.f};
    f32x4 acc[4][4];
#pragma unroll
    for (int i = 0; i < 4; i++)
#pragma unroll
        for (int j = 0; j < 4; j++) acc[i][j] = zero4;
    for (int k0 = 0; k0 < K; k0 += 32) {
        uint4  av[2];
        float4 bv[4];
#pragma unroll
        for (int i = 0; i < 2; i++) {
            int c = i * 256 + t, row = c >> 2, kc = c & 3;
            av[i] = *(const uint4*)(A + (size_t)(m0 + row) * K + k0 + kc * 8);
        }
#pragma unroll
        for (int i = 0; i < 4; i++) {
            int c = i * 256 + t, row = c >> 3, kc = c & 7;
            int gr = n0 + row; if (gr > N - 1) gr = N - 1;
            bv[i] = *(const float4*)(B + (size_t)gr * K + k0 + kc * 4);
        }
        __syncthreads();
#pragma unroll
        for (int i = 0; i < 2; i++) {
            int c = i * 256 + t, row = c >> 2, kc = c & 3;
            *(uint4*)(As + row * LDSK + kc * 8) = av[i];
        }
#pragma unroll
        for (int i = 0; i < 4; i++) {
            int c = i * 256 + t, row = c >> 3, kc = c & 7;
            short4v sv;
            sv.x = f2bf(bv[i].x); sv.y = f2bf(bv[i].y);
            sv.z = f2bf(bv[i].z); sv.w = f2bf(bv[i].w);
            *(short4v*)(Bs + row * LDSK + kc * 4) = sv;
        }
        __syncthreads();
        short8 af[4], bf[4];
#pragma unroll
        for (int mt = 0; mt < 4; mt++)
            af[mt] = *(const short8*)(As + (wm + mt * 16 + (lane & 15)) * LDSK + (lane >> 4) * 8);
#pragma unroll
        for (int nt = 0; nt < 4; nt++)
            bf[nt] = *(const short8*)(Bs + (wn + nt * 16 + (lane & 15)) * LDSK + (lane >> 4) * 8);
#pragma unroll
        for (int mt = 0; mt < 4; mt++)
#pragma unroll
            for (int nt = 0; nt < 4; nt++)
                acc[mt][nt] = __builtin_amdgcn_mfma_f32_16x16x32_bf16(af[mt], bf[nt], acc[mt][nt], 0, 0, 0);
    }
#pragma unroll
    for (int mt = 0; mt < 4; mt++) {
        int row = m0 + wm + mt * 16 + (lane >> 4) * 4;
#pragma unroll
        for (int nt = 0; nt < 4; nt++) {
            int col = n0 + wn + nt * 16 + (lane & 15);
            if (col < N) {
#pragma unroll
                for (int r = 0; r < 4; r++) {
                    size_t o = (size_t)(row + r) * N + col;
                    float val = acc[mt][nt][r];
                    if (addflag) C[o] += val; else C[o] = val;
                }
            }
        }
    }
}

// -------- fused depthwise causal conv (win 4) + bias + SiLU, and dt/dA ----------
__global__ void convdt_k(const float* __restrict__ zx, const float* __restrict__ cw,
                         const float* __restrict__ cb, const float* __restrict__ dt_bias,
                         const float* __restrict__ A_log, float* __restrict__ xbc,
                         float* __restrict__ dts, float* __restrict__ dAv) {
    int c = blockIdx.x * 256 + threadIdx.x;
    int t = blockIdx.y;
    if (c < CONVDIM) {
        float acc = cb[c];
#pragma unroll
        for (int j = 0; j < 4; j++) {
            int ts = t - 3 + j;
            if (ts >= 0) acc += cw[c * 4 + j] * zx[(size_t)ts * DINPROJ + DINNER + c];
        }
        xbc[(size_t)t * CONVDIM + c] = acc / (1.f + __expf(-acc));
    } else if (c < CONVDIM + NHEADS) {
        int h = c - CONVDIM;
        float d = zx[(size_t)t * DINPROJ + 3200 + h] + dt_bias[h];
        float sp = (d > 20.f) ? d : log1pf(__expf(d));
        dts[t * NHEADS + h] = sp;
        dAv[t * NHEADS + h] = __expf(-__expf(A_log[h]) * sp);
    }
}

// ---------------- sequential SSM scan v5 ----------------
// 384 blocks (24 heads x 16 p-groups of 4), 256 threads (4 waves) — fills all CUs.
// Wave wv owns n-quarter wv (16 n); pl = lane>>4 (4 p), n4 = lane&15 (16 n).
// Same per-step chain as v4: 1 recurrence fma + mul + 4 DPP; reduce -> n4==0.
// Partial y combined via ys[64][4][4] (4 KB) per 64-step chunk.
__global__ __launch_bounds__(256) void scan_k(const float* __restrict__ xbc,
                                              const float* __restrict__ dts,
                                              const float* __restrict__ dAv,
                                              float* __restrict__ yraw) {
    __shared__ __align__(16) float BCs[64][128];
    __shared__ __align__(16) float xs[64][4];
    __shared__ float dash[64];
    __shared__ float ys[64][4][4];
    int h = blockIdx.x >> 4;               // 0..23
    int pbase = (blockIdx.x & 15) * 4;     // 0..60
    int t = threadIdx.x, lane = t & 63, wv = t >> 6;
    int nq = wv;                           // n-quarter 0..3
    int pl = lane >> 4;                    // 0..3
    int n4 = lane & 15;
    int nbase = nq * 16;
    float s0 = 0.f;

    for (int tc = 0; tc < 16; tc++) {
        __syncthreads();
#pragma unroll 4
        for (int it = 0; it < 8; it++) {
            int idx = it * 256 + t;
            int trow = idx >> 5, c4 = idx & 31;
            *(float4*)&BCs[trow][c4 * 4] =
                *(const float4*)(xbc + (size_t)(tc * 64 + trow) * CONVDIM + DINNER + c4 * 4);
        }
        if (t < 64) {
            float dtv = dts[(tc * 64 + t) * NHEADS + h];
            float4 xv = *(const float4*)(xbc + (size_t)(tc * 64 + t) * CONVDIM
                                         + h * HEADDIM + pbase);
            xv.x *= dtv; xv.y *= dtv; xv.z *= dtv; xv.w *= dtv;
            *(float4*)&xs[t][0] = xv;
            dash[t] = dAv[(tc * 64 + t) * NHEADS + h];
        }
        __syncthreads();

#pragma unroll 4
        for (int tt = 0; tt < 64; tt++) {
            float Bv = BCs[tt][nbase + n4];
            float Cv = BCs[tt][64 + nbase + n4];
            float dtx = xs[tt][pl];
            float da = dash[tt];
            s0 = fmaf(da, s0, dtx * Bv);
            float part = s0 * Cv;
            part = dppadd<0xB1>(part);    // quad_perm [1,0,3,2]  (xor 1)
            part = dppadd<0x4E>(part);    // quad_perm [2,3,0,1]  (xor 2)
            part = dppadd<0x114>(part);   // row_shr:4
            part = dppadd<0x118>(part);   // row_shr:8
            if (n4 == 0) ys[tt][pl][nq] = part;
        }
        __syncthreads();
        // combine quarters and write this chunk's y (256 threads = 64x4 exactly)
        {
            int tt2 = t >> 2, pl2 = t & 3;
            float yv = ys[tt2][pl2][0] + ys[tt2][pl2][1] + ys[tt2][pl2][2] + ys[tt2][pl2][3];
            yraw[(size_t)(tc * 64 + tt2) * DINNER + h * HEADDIM + pbase + pl2] = yv;
        }
    }
}

// ---------------- (y + Dp*xh) * silu(z), RMS norm, * rms_w -> bf16 ----------------
__global__ void rms_k(const float* __restrict__ yraw, const float* __restrict__ zx,
                      const float* __restrict__ xbc, const float* __restrict__ Dp,
                      const float* __restrict__ rw, short* __restrict__ yn) {
    int row = blockIdx.x, t = threadIdx.x;
    float v[6];
    float q = 0.f;
#pragma unroll
    for (int j = 0; j < 6; j++) {
        int i = t + j * 256;
        float z  = zx[(size_t)row * DINPROJ + i];
        float xh = xbc[(size_t)row * CONVDIM + i];
        float y  = yraw[(size_t)row * DINNER + i] + Dp[i >> 6] * xh;
        float val = y * (z / (1.f + __expf(-z)));
        v[j] = val;
        q += val * val;
    }
    __shared__ float sb[4];
    for (int off = 32; off; off >>= 1) q += __shfl_down(q, off);
    if (!(t & 63)) sb[t >> 6] = q;
    __syncthreads();
    q = sb[0] + sb[1] + sb[2] + sb[3];
    float rs = rsqrtf(q * (1.f / DINNER) + 1e-5f);
#pragma unroll
    for (int j = 0; j < 6; j++) {
        int i = t + j * 256;
        yn[(size_t)row * DINNER + i] = f2bf(v[j] * rs * rw[i]);
    }
}

// ---------------- per-row online logsumexp + NLL (fallback path) ----------------
__global__ void loss_row_k(const float* __restrict__ logits, const int* __restrict__ tg,
                           float* __restrict__ lossp) {
    int r = blockIdx.x, t = threadIdx.x;
    const float* lr = logits + (size_t)r * VOCABN;
    float m = -3.0e38f, s = 0.f;
    for (int j = t; j < VOCABN; j += 256) {
        float v = lr[j];
        if (v > m) { s = s * __expf(m - v) + 1.f; m = v; }
        else s += __expf(v - m);
    }
    for (int off = 32; off; off >>= 1) {
        float mo = __shfl_down(m, off), so = __shfl_down(s, off);
        float nm = fmaxf(m, mo);
        s = s * __expf(m - nm) + so * __expf(mo - nm);
        m = nm;
    }
    __shared__ float sm[4], ss[4];
    if (!(t & 63)) { sm[t >> 6] = m; ss[t >> 6] = s; }
    __syncthreads();
    if (t == 0) {
        m = sm[0]; s = ss[0];
        for (int w = 1; w < 4; w++) {
            float nm = fmaxf(m, sm[w]);
            s = s * __expf(m - nm) + ss[w] * __expf(sm[w] - nm);
            m = nm;
        }
        lossp[r] = (m + logf(s)) - lr[tg[r]];
    }
}

// ---------------- combine per-panel (m,s) partials -> per-row NLL ----------------
__global__ void loss_fin2_k(const float2* __restrict__ P, const float* __restrict__ logits,
                            const int* __restrict__ tg, float* __restrict__ lossp) {
    int r = blockIdx.x * 256 + threadIdx.x;
    float m = -3.0e38f;
    for (int p = 0; p < 197; p++)
        m = fmaxf(m, P[(size_t)p * 1024 + r].x);
    float s = 0.f;
    for (int p = 0; p < 197; p++) {
        float2 q = P[(size_t)p * 1024 + r];
        s += q.y * __expf(q.x - m);
    }
    lossp[r] = (m + logf(s)) - logits[(size_t)r * VOCABN + tg[r]];
}

__global__ void loss_fin_k(const float* __restrict__ lossp, float* __restrict__ out) {
    int t = threadIdx.x;
    float s = lossp[t] + lossp[t + 256] + lossp[t + 512] + lossp[t + 768];
    for (int off = 32; off; off >>= 1) s += __shfl_down(s, off);
    __shared__ float sb[4];
    if (!(t & 63)) sb[t >> 6] = s;
    __syncthreads();
    if (t == 0) out[(size_t)SL * VOCABN] = (sb[0] + sb[1] + sb[2] + sb[3]) * (1.f / SL);
}

// ---------------- driver ----------------
extern "C" void kernel_launch(void* const* d_in, const int* in_sizes, int n_in,
                              void* d_out, int out_size, void* d_ws, size_t ws_size,
                              hipStream_t stream) {
    const int*   idx     = (const int*)d_in[0];
    const int*   targets = (const int*)d_in[1];
    const float* emb     = (const float*)d_in[2];
    const float* ln_w    = (const float*)d_in[3];
    const float* ln_b    = (const float*)d_in[4];
    const float* W_in    = (const float*)d_in[5];
    const float* conv_w  = (const float*)d_in[6];
    const float* conv_b  = (const float*)d_in[7];
    const float* dt_bias = (const float*)d_in[8];
    const float* A_log   = (const float*)d_in[9];
    const float* Dp      = (const float*)d_in[10];
    const float* rms_w   = (const float*)d_in[11];
    const float* W_out   = (const float*)d_in[12];
    const float* lnf_w   = (const float*)d_in[13];
    const float* lnf_b   = (const float*)d_in[14];

    char* ws = (char*)d_ws;
    float* x     = (float*)(ws + 0);
    short* xn    = (short*)(ws + 3145728);
    float* zx    = (float*)(ws + 4718592);
    float* xbc   = (float*)(ws + 17924096);
    float* dts   = (float*)(ws + 24739840);
    float* dAv   = (float*)(ws + 24838144);
    float* yraw  = (float*)(ws + 24936448);
    short* yn    = (short*)(ws + 31227904);
    float* lossp = (float*)(ws + 34373632);
    short* wInb  = (short*)(ws + 34377728);   // 19,806,208 B
    short* wOutb = (short*)(ws + 54183936);   //  9,437,184 B
    short* embb  = (short*)(ws + 63621120);   // 77,194,752 B
    float2* pms  = (float2*)(ws + 4718592);   // reuse zx space (dead at logits time)
    float* logits = (float*)d_out;

    const bool big = ws_size >= 140815872ull;

    if (big) {
        int nWin  = NLAYER * DINPROJ * DMODEL;   // 9,903,104
        int nWout = NLAYER * DMODEL * DINNER;    // 4,718,592
        int nEmb  = VOCABN * DMODEL;             // 38,597,376
        cvt_k<<<(nWin / 4 + 255) / 256, 256, 0, stream>>>(W_in, wInb, nWin);
        cvt_k<<<(nWout / 4 + 255) / 256, 256, 0, stream>>>(W_out, wOutb, nWout);
        cvt_k<<<(nEmb / 4 + 255) / 256, 256, 0, stream>>>(emb, embb, nEmb);
    }

    embed_k<<<dim3(3, SL), 256, 0, stream>>>(idx, emb, x);
    for (int l = 0; l < NLAYER; l++) {
        ln_k<<<SL, 256, 0, stream>>>(x, ln_w + l * DMODEL, ln_b + l * DMODEL, xn);
        if (big)
            gemm128_k<<<208, 256, 0, stream>>>(xn, wInb + (size_t)l * DINPROJ * DMODEL,
                                               zx, DINPROJ, DMODEL, 0, 8);
        else
            gemm_bt_k<<<dim3(8, 26), 256, 0, stream>>>(xn, W_in + (size_t)l * DINPROJ * DMODEL,
                                                       zx, DINPROJ, DMODEL, 0);
        convdt_k<<<dim3(7, SL), 256, 0, stream>>>(zx, conv_w + l * CONVDIM * 4,
                                                  conv_b + l * CONVDIM,
                                                  dt_bias + l * NHEADS, A_log + l * NHEADS,
                                                  xbc, dts, dAv);
        scan_k<<<384, 256, 0, stream>>>(xbc, dts, dAv, yraw);
        rms_k<<<SL, 256, 0, stream>>>(yraw, zx, xbc, Dp + l * NHEADS, rms_w + l * DINNER, yn);
        if (big)
            gemm64_k<<<192, 256, 0, stream>>>(yn, wOutb + (size_t)l * DMODEL * DINNER,
                                              x, DMODEL, DINNER, 1, 16);
        else
            gemm_bt_k<<<dim3(8, 6), 256, 0, stream>>>(yn, W_out + (size_t)l * DMODEL * DINNER,
                                                      x, DMODEL, DINNER, 1);
    }
    ln_k<<<SL, 256, 0, stream>>>(x, lnf_w, lnf_b, xn);
    if (big) {
        gemm_bb_k<<<4 * 197, 512, 0, stream>>>(xn, embb, logits, pms, VOCABN, DMODEL, 0);
        loss_fin2_k<<<4, 256, 0, stream>>>(pms, logits, targets, lossp);
    } else {
        gemm_bt_k<<<dim3(8, 393), 256, 0, stream>>>(xn, emb, logits, VOCABN, DMODEL, 0);
        loss_row_k<<<SL, 256, 0, stream>>>(logits, targets, lossp);
    }
    loss_fin_k<<<1, 256, 0, stream>>>(lossp, logits);
}